// Round 1
// baseline (148.841 us; speedup 1.0000x reference)
//
#include <hip/hip_runtime.h>

// Problem constants (from reference): B=1024, D_IN=64, D_HID=128.
#define BB      1024
#define DIN     64
#define DHID    128
#define NPAIRS  (1024.0f * 1024.0f)
#define BN_EPS  1e-5f

// ---------------------------------------------------------------------------
// K1: U[i][c] = x[i,:] . W1[0:64, c] + b1[c]
//     V[j][c] = x[j,:] . W1[64:128, c]
// Store Vj (j-major, for stats kernel) and Vt (c-major, for output kernel).
// Grid: 128 blocks x 256 threads; each block handles 8 rows of x.
// ---------------------------------------------------------------------------
__global__ __launch_bounds__(256) void k1_proj(
    const float* __restrict__ x, const float* __restrict__ W1,
    const float* __restrict__ b1,
    float* __restrict__ Ub, float* __restrict__ Vj, float* __restrict__ Vt)
{
    __shared__ float xs[8][DIN];
    const int c     = threadIdx.x & 127;
    const int half  = threadIdx.x >> 7;      // 0..1
    const int rbase = blockIdx.x * 8;

    // stage 8 x-rows (512 floats) into LDS
    for (int t = threadIdx.x; t < 8 * DIN; t += 256)
        xs[t >> 6][t & 63] = x[(rbase + (t >> 6)) * DIN + (t & 63)];
    __syncthreads();

    float u[4] = {0.f, 0.f, 0.f, 0.f};
    float v[4] = {0.f, 0.f, 0.f, 0.f};
    const int r0 = half * 4;
    for (int k = 0; k < DIN; ++k) {
        const float wt = W1[k * DHID + c];          // coalesced over c
        const float wb = W1[(DIN + k) * DHID + c];
        #pragma unroll
        for (int r = 0; r < 4; ++r) {
            const float xv = xs[r0 + r][k];          // LDS broadcast
            u[r] = fmaf(xv, wt, u[r]);
            v[r] = fmaf(xv, wb, v[r]);
        }
    }
    const float bb = b1[c];
    #pragma unroll
    for (int r = 0; r < 4; ++r) {
        const int row = rbase + r0 + r;
        Ub[row * DHID + c] = u[r] + bb;
        Vj[row * DHID + c] = v[r];
        Vt[c * BB + row]   = v[r];   // small scattered store, 512 KB total
    }
}

// ---------------------------------------------------------------------------
// K2: per-channel sum and sum-of-squares of relu(U[i,c] + V[j,c]) over all
// (i, j). Grid: 256 blocks x 256 threads; block handles 4 i's, all j.
// Thread owns 4 channels (float4) and a j-stride-of-8 lane.
// sums[0..127] = sum, sums[128..255] = sumsq (pre-zeroed via memsetAsync).
// ---------------------------------------------------------------------------
__global__ __launch_bounds__(256) void k2_stats(
    const float* __restrict__ Ub, const float* __restrict__ Vj,
    float* __restrict__ sums)
{
    const int cg  = threadIdx.x & 31;   // channel group
    const int c0  = cg * 4;
    const int jl  = threadIdx.x >> 5;   // 0..7
    const int ib  = blockIdx.x * 4;

    float4 u[4];
    #pragma unroll
    for (int ii = 0; ii < 4; ++ii)
        u[ii] = *(const float4*)&Ub[(ib + ii) * DHID + c0];

    float4 s = {0.f, 0.f, 0.f, 0.f};
    float4 q = {0.f, 0.f, 0.f, 0.f};
    #pragma unroll 2
    for (int j = jl; j < BB; j += 8) {
        const float4 v = *(const float4*)&Vj[j * DHID + c0];
        #pragma unroll
        for (int ii = 0; ii < 4; ++ii) {
            float t;
            t = fmaxf(u[ii].x + v.x, 0.f); s.x += t; q.x = fmaf(t, t, q.x);
            t = fmaxf(u[ii].y + v.y, 0.f); s.y += t; q.y = fmaf(t, t, q.y);
            t = fmaxf(u[ii].z + v.z, 0.f); s.z += t; q.z = fmaf(t, t, q.z);
            t = fmaxf(u[ii].w + v.w, 0.f); s.w += t; q.w = fmaf(t, t, q.w);
        }
    }

    __shared__ float ls[8][DHID];
    __shared__ float lq[8][DHID];
    *(float4*)&ls[jl][c0] = s;
    *(float4*)&lq[jl][c0] = q;
    __syncthreads();

    if (threadIdx.x < 32) {
        float4 S = *(float4*)&ls[0][c0];
        float4 Q = *(float4*)&lq[0][c0];
        for (int g = 1; g < 8; ++g) {
            S.x += ls[g][c0 + 0]; S.y += ls[g][c0 + 1];
            S.z += ls[g][c0 + 2]; S.w += ls[g][c0 + 3];
            Q.x += lq[g][c0 + 0]; Q.y += lq[g][c0 + 1];
            Q.z += lq[g][c0 + 2]; Q.w += lq[g][c0 + 3];
        }
        atomicAdd(&sums[c0 + 0], S.x); atomicAdd(&sums[c0 + 1], S.y);
        atomicAdd(&sums[c0 + 2], S.z); atomicAdd(&sums[c0 + 3], S.w);
        atomicAdd(&sums[DHID + c0 + 0], Q.x); atomicAdd(&sums[DHID + c0 + 1], Q.y);
        atomicAdd(&sums[DHID + c0 + 2], Q.z); atomicAdd(&sums[DHID + c0 + 3], Q.w);
    }
}

// ---------------------------------------------------------------------------
// K3: out[i,j] = t + sum_c relu(U[i,c] + V[j,c]) * s[c]
// Each block computes s[] and t from the channel sums (cheap: 128 channels),
// then does a 4-i x 1024-j tile; thread owns 4 consecutive j (float4 loads of
// Vt). Grid: 256 blocks x 256 threads.
// ---------------------------------------------------------------------------
__global__ __launch_bounds__(256) void k3_out(
    const float* __restrict__ Ub, const float* __restrict__ Vt,
    const float* __restrict__ sums,
    const float* __restrict__ gamma, const float* __restrict__ beta,
    const float* __restrict__ W2, const float* __restrict__ b2,
    float* __restrict__ out)
{
    __shared__ float lsc[DHID];
    __shared__ float lus[4][DHID];
    __shared__ float ltp[DHID];
    __shared__ float lt;

    const int tid = threadIdx.x;
    const int ib  = blockIdx.x * 4;

    if (tid < DHID) {
        const float invN = 1.0f / NPAIRS;
        const float mean = sums[tid] * invN;
        const float var  = fmaxf(sums[DHID + tid] * invN - mean * mean, 0.f);
        const float inv  = rsqrtf(var + BN_EPS);
        const float gi   = gamma[tid] * inv;
        const float w2   = W2[tid];
        lsc[tid] = gi * w2;
        ltp[tid] = (beta[tid] - mean * gi) * w2;
    }
    // stage 4 rows of U (512 floats) into LDS
    {
        int t = tid;
        lus[t >> 7][t & 127] = Ub[(ib + (t >> 7)) * DHID + (t & 127)];
        t += 256;
        lus[t >> 7][t & 127] = Ub[(ib + (t >> 7)) * DHID + (t & 127)];
    }
    __syncthreads();
    for (int off = 64; off >= 1; off >>= 1) {   // uniform control flow
        if (tid < off) ltp[tid] += ltp[tid + off];
        __syncthreads();
    }
    if (tid == 0) lt = ltp[0] + b2[0];
    __syncthreads();
    const float tconst = lt;

    const int j0 = tid * 4;
    float4 a0 = {0.f,0.f,0.f,0.f}, a1 = {0.f,0.f,0.f,0.f};
    float4 a2 = {0.f,0.f,0.f,0.f}, a3 = {0.f,0.f,0.f,0.f};

    #pragma unroll 4
    for (int c = 0; c < DHID; ++c) {
        const float4 v = *(const float4*)&Vt[c * BB + j0];  // coalesced
        const float sc = lsc[c];                            // LDS broadcast
        const float u0 = lus[0][c], u1 = lus[1][c];
        const float u2 = lus[2][c], u3 = lus[3][c];
        a0.x = fmaf(fmaxf(u0 + v.x, 0.f), sc, a0.x);
        a0.y = fmaf(fmaxf(u0 + v.y, 0.f), sc, a0.y);
        a0.z = fmaf(fmaxf(u0 + v.z, 0.f), sc, a0.z);
        a0.w = fmaf(fmaxf(u0 + v.w, 0.f), sc, a0.w);
        a1.x = fmaf(fmaxf(u1 + v.x, 0.f), sc, a1.x);
        a1.y = fmaf(fmaxf(u1 + v.y, 0.f), sc, a1.y);
        a1.z = fmaf(fmaxf(u1 + v.z, 0.f), sc, a1.z);
        a1.w = fmaf(fmaxf(u1 + v.w, 0.f), sc, a1.w);
        a2.x = fmaf(fmaxf(u2 + v.x, 0.f), sc, a2.x);
        a2.y = fmaf(fmaxf(u2 + v.y, 0.f), sc, a2.y);
        a2.z = fmaf(fmaxf(u2 + v.z, 0.f), sc, a2.z);
        a2.w = fmaf(fmaxf(u2 + v.w, 0.f), sc, a2.w);
        a3.x = fmaf(fmaxf(u3 + v.x, 0.f), sc, a3.x);
        a3.y = fmaf(fmaxf(u3 + v.y, 0.f), sc, a3.y);
        a3.z = fmaf(fmaxf(u3 + v.z, 0.f), sc, a3.z);
        a3.w = fmaf(fmaxf(u3 + v.w, 0.f), sc, a3.w);
    }

    float4 o;
    o.x = a0.x + tconst; o.y = a0.y + tconst; o.z = a0.z + tconst; o.w = a0.w + tconst;
    *(float4*)&out[(ib + 0) * BB + j0] = o;
    o.x = a1.x + tconst; o.y = a1.y + tconst; o.z = a1.z + tconst; o.w = a1.w + tconst;
    *(float4*)&out[(ib + 1) * BB + j0] = o;
    o.x = a2.x + tconst; o.y = a2.y + tconst; o.z = a2.z + tconst; o.w = a2.w + tconst;
    *(float4*)&out[(ib + 2) * BB + j0] = o;
    o.x = a3.x + tconst; o.y = a3.y + tconst; o.z = a3.z + tconst; o.w = a3.w + tconst;
    *(float4*)&out[(ib + 3) * BB + j0] = o;
}

extern "C" void kernel_launch(void* const* d_in, const int* in_sizes, int n_in,
                              void* d_out, int out_size, void* d_ws, size_t ws_size,
                              hipStream_t stream) {
    const float* x     = (const float*)d_in[0];  // (1024, 64)
    const float* W1    = (const float*)d_in[1];  // (128, 128)
    const float* b1    = (const float*)d_in[2];  // (128,)
    const float* gamma = (const float*)d_in[3];  // (128,)
    const float* beta  = (const float*)d_in[4];  // (128,)
    const float* W2    = (const float*)d_in[5];  // (128,)
    const float* b2    = (const float*)d_in[6];  // (1,)
    float* out = (float*)d_out;                  // (1024*1024,)

    float* ws   = (float*)d_ws;
    float* Ub   = ws;                 // 1024*128
    float* Vj   = ws + 131072;        // 1024*128 (j-major)
    float* Vt   = ws + 262144;        // 128*1024 (c-major)
    float* sums = ws + 393216;        // 256 (sum | sumsq)

    hipMemsetAsync(sums, 0, 256 * sizeof(float), stream);
    k1_proj<<<128, 256, 0, stream>>>(x, W1, b1, Ub, Vj, Vt);
    k2_stats<<<256, 256, 0, stream>>>(Ub, Vj, sums);
    k3_out<<<256, 256, 0, stream>>>(Ub, Vt, sums, gamma, beta, W2, b2, out);
}

// Round 2
// 109.495 us; speedup vs baseline: 1.3593x; 1.3593x over previous
//
#include <hip/hip_runtime.h>

// Problem constants (from reference): B=1024, D_IN=64, D_HID=128.
#define BB      1024
#define DIN     64
#define DHID    128
#define NPAIRS  (1024.0f * 1024.0f)
#define BN_EPS  1e-5f

// ---------------------------------------------------------------------------
// K1: U[i][c] = x[i,:] . W1[0:64, c] + b1[c]
//     V[j][c] = x[j,:] . W1[64:128, c]
// Store Vj (j-major, for stats kernel) and Vt (c-major, for output kernel).
// Grid: 256 blocks x 256 threads; each block handles 4 rows of x.
// ---------------------------------------------------------------------------
__global__ __launch_bounds__(256) void k1_proj(
    const float* __restrict__ x, const float* __restrict__ W1,
    const float* __restrict__ b1,
    float* __restrict__ Ub, float* __restrict__ Vj, float* __restrict__ Vt)
{
    __shared__ float xs[4][DIN];
    const int c     = threadIdx.x & 127;
    const int half  = threadIdx.x >> 7;      // 0..1
    const int rbase = blockIdx.x * 4;

    // stage 4 x-rows (256 floats) into LDS: exactly one float per thread
    xs[threadIdx.x >> 6][threadIdx.x & 63] = x[rbase * DIN + threadIdx.x];
    __syncthreads();

    float u0 = 0.f, u1 = 0.f, v0 = 0.f, v1 = 0.f;
    const int r0 = half * 2;
    #pragma unroll 8
    for (int k = 0; k < DIN; ++k) {
        const float wt = W1[k * DHID + c];          // coalesced over c
        const float wb = W1[(DIN + k) * DHID + c];
        const float x0 = xs[r0][k];                  // LDS broadcast
        const float x1 = xs[r0 + 1][k];
        u0 = fmaf(x0, wt, u0); v0 = fmaf(x0, wb, v0);
        u1 = fmaf(x1, wt, u1); v1 = fmaf(x1, wb, v1);
    }
    const float bbv = b1[c];
    const int row0 = rbase + r0;
    Ub[row0 * DHID + c]       = u0 + bbv;
    Vj[row0 * DHID + c]       = v0;
    Vt[c * BB + row0]         = v0;
    Ub[(row0 + 1) * DHID + c] = u1 + bbv;
    Vj[(row0 + 1) * DHID + c] = v1;
    Vt[c * BB + row0 + 1]     = v1;
}

// ---------------------------------------------------------------------------
// K2: per-channel sum / sumsq of relu(U[i,c] + V[j,c]).
// Grid: dim3(128, 4) x 256 threads. Block = 8 i-rows x 256 j's.
// Thread: 4 channels (float4) x 8 u-rows IN REGISTERS, j-stride-8 lane.
// 96 VALU insts per 16B load (~192 cy) -> latency fully covered even at
// modest occupancy; 512 blocks = 2 blocks/CU = 8 waves/CU.
// Writes per-block partials (no atomics): partial[bid][0..127]=sum,
// partial[bid][128..255]=sumsq.
// ---------------------------------------------------------------------------
__global__ __launch_bounds__(256) void k2_stats(
    const float* __restrict__ Ub, const float* __restrict__ Vj,
    float* __restrict__ partial)
{
    const int c0    = (threadIdx.x & 31) * 4;   // channel group
    const int jl    = threadIdx.x >> 5;         // 0..7
    const int ib    = blockIdx.x * 8;           // 8 i's
    const int jbase = blockIdx.y * 256;         // 256 j's

    float4 u[8];
    #pragma unroll
    for (int ii = 0; ii < 8; ++ii)
        u[ii] = *(const float4*)&Ub[(ib + ii) * DHID + c0];

    float4 s = {0.f, 0.f, 0.f, 0.f};
    float4 q = {0.f, 0.f, 0.f, 0.f};
    #pragma unroll 2
    for (int t = 0; t < 32; ++t) {
        const float4 v = *(const float4*)&Vj[(jbase + jl + 8 * t) * DHID + c0];
        #pragma unroll
        for (int ii = 0; ii < 8; ++ii) {
            float r;
            r = fmaxf(u[ii].x + v.x, 0.f); s.x += r; q.x = fmaf(r, r, q.x);
            r = fmaxf(u[ii].y + v.y, 0.f); s.y += r; q.y = fmaf(r, r, q.y);
            r = fmaxf(u[ii].z + v.z, 0.f); s.z += r; q.z = fmaf(r, r, q.z);
            r = fmaxf(u[ii].w + v.w, 0.f); s.w += r; q.w = fmaf(r, r, q.w);
        }
    }

    __shared__ float ls[8][DHID];
    __shared__ float lq[8][DHID];
    *(float4*)&ls[jl][c0] = s;
    *(float4*)&lq[jl][c0] = q;
    __syncthreads();

    if (threadIdx.x < 32) {
        float4 S = *(float4*)&ls[0][c0];
        float4 Q = *(float4*)&lq[0][c0];
        #pragma unroll
        for (int g = 1; g < 8; ++g) {
            S.x += ls[g][c0 + 0]; S.y += ls[g][c0 + 1];
            S.z += ls[g][c0 + 2]; S.w += ls[g][c0 + 3];
            Q.x += lq[g][c0 + 0]; Q.y += lq[g][c0 + 1];
            Q.z += lq[g][c0 + 2]; Q.w += lq[g][c0 + 3];
        }
        const int bid = blockIdx.y * 128 + blockIdx.x;   // 0..511
        *(float4*)&partial[bid * 256 + c0]        = S;
        *(float4*)&partial[bid * 256 + DHID + c0] = Q;
    }
}

// ---------------------------------------------------------------------------
// K2b: reduce partial[512][256] -> sums[256]. Plain stores, no atomics,
// no memset needed. Grid: 16 blocks x 256 threads, 16 columns per block.
// ---------------------------------------------------------------------------
__global__ __launch_bounds__(256) void k2b_reduce(
    const float* __restrict__ partial, float* __restrict__ sums)
{
    __shared__ float lred[16][17];
    const int cl   = threadIdx.x & 15;          // column-in-block
    const int rg   = threadIdx.x >> 4;          // 0..15 row group
    const int col  = blockIdx.x * 16 + cl;

    float acc = 0.f;
    #pragma unroll 4
    for (int t = 0; t < 32; ++t)
        acc += partial[(rg + 16 * t) * 256 + col];
    lred[rg][cl] = acc;
    __syncthreads();
    if (threadIdx.x < 16) {
        float a = 0.f;
        #pragma unroll
        for (int g = 0; g < 16; ++g) a += lred[g][threadIdx.x];
        sums[blockIdx.x * 16 + threadIdx.x] = a;
    }
}

// ---------------------------------------------------------------------------
// K3: out[i,j] = t + sum_c relu(U[i,c] + V[j,c]) * s[c]
// Grid: dim3(128, 4) x 256 threads. Block = 8 i-rows x 256 j's.
// Thread: 4 i (from LDS broadcast) x 2 j (float2 of c-major Vt), 24 VALU
// per 8B load; 512 blocks = 2 blocks/CU = 8 waves/CU.
// ---------------------------------------------------------------------------
__global__ __launch_bounds__(256) void k3_out(
    const float* __restrict__ Ub, const float* __restrict__ Vt,
    const float* __restrict__ sums,
    const float* __restrict__ gamma, const float* __restrict__ beta,
    const float* __restrict__ W2, const float* __restrict__ b2,
    float* __restrict__ out)
{
    __shared__ float lsc[DHID];
    __shared__ float lus[8][DHID];
    __shared__ float ltp[DHID];
    __shared__ float lt;

    const int tid   = threadIdx.x;
    const int ib    = blockIdx.x * 8;
    const int jbase = blockIdx.y * 256;

    if (tid < DHID) {
        const float invN = 1.0f / NPAIRS;
        const float mean = sums[tid] * invN;
        const float var  = fmaxf(sums[DHID + tid] * invN - mean * mean, 0.f);
        const float inv  = rsqrtf(var + BN_EPS);
        const float gi   = gamma[tid] * inv;
        const float w2   = W2[tid];
        lsc[tid] = gi * w2;
        ltp[tid] = (beta[tid] - mean * gi) * w2;
    }
    // stage 8 rows of U (1024 floats) into LDS
    #pragma unroll
    for (int t = tid; t < 8 * DHID; t += 256)
        lus[t >> 7][t & 127] = Ub[(ib + (t >> 7)) * DHID + (t & 127)];
    __syncthreads();
    for (int off = 64; off >= 1; off >>= 1) {   // uniform control flow
        if (tid < off) ltp[tid] += ltp[tid + off];
        __syncthreads();
    }
    if (tid == 0) lt = ltp[0] + b2[0];
    __syncthreads();
    const float tconst = lt;

    const int i0 = (tid >> 7) * 4;              // 0 or 4
    const int j0 = jbase + (tid & 127) * 2;

    float a[4][2] = {};
    #pragma unroll 4
    for (int c = 0; c < DHID; ++c) {
        const float2 v = *(const float2*)&Vt[c * BB + j0];  // coalesced 8B
        const float sc = lsc[c];                            // LDS broadcast
        #pragma unroll
        for (int ii = 0; ii < 4; ++ii) {
            const float uu = lus[i0 + ii][c];               // LDS broadcast
            a[ii][0] = fmaf(fmaxf(uu + v.x, 0.f), sc, a[ii][0]);
            a[ii][1] = fmaf(fmaxf(uu + v.y, 0.f), sc, a[ii][1]);
        }
    }
    #pragma unroll
    for (int ii = 0; ii < 4; ++ii) {
        float2 o;
        o.x = a[ii][0] + tconst;
        o.y = a[ii][1] + tconst;
        *(float2*)&out[(ib + i0 + ii) * BB + j0] = o;
    }
}

extern "C" void kernel_launch(void* const* d_in, const int* in_sizes, int n_in,
                              void* d_out, int out_size, void* d_ws, size_t ws_size,
                              hipStream_t stream) {
    const float* x     = (const float*)d_in[0];  // (1024, 64)
    const float* W1    = (const float*)d_in[1];  // (128, 128)
    const float* b1    = (const float*)d_in[2];  // (128,)
    const float* gamma = (const float*)d_in[3];  // (128,)
    const float* beta  = (const float*)d_in[4];  // (128,)
    const float* W2    = (const float*)d_in[5];  // (128,)
    const float* b2    = (const float*)d_in[6];  // (1,)
    float* out = (float*)d_out;                  // (1024*1024,)

    float* ws      = (float*)d_ws;
    float* Ub      = ws;                 // 1024*128
    float* Vj      = ws + 131072;        // 1024*128 (j-major)
    float* Vt      = ws + 262144;        // 128*1024 (c-major)
    float* partial = ws + 393216;        // 512*256 block partials
    float* sums    = ws + 524288;        // 256 (sum | sumsq)

    k1_proj<<<256, 256, 0, stream>>>(x, W1, b1, Ub, Vj, Vt);
    k2_stats<<<dim3(128, 4), 256, 0, stream>>>(Ub, Vj, partial);
    k2b_reduce<<<16, 256, 0, stream>>>(partial, sums);
    k3_out<<<dim3(128, 4), 256, 0, stream>>>(Ub, Vt, sums, gamma, beta, W2, b2, out);
}